// Round 3
// baseline (120.954 us; speedup 1.0000x reference)
//
#include <hip/hip_runtime.h>

#define BLOCK 256
#define NBLOCKS 2048
#define BLOCK2 256

// Clang ext vector types so __builtin_nontemporal_load works on 16B chunks.
typedef float v4f __attribute__((ext_vector_type(4)));
typedef int   v4i __attribute__((ext_vector_type(4)));

// -log softmax at target t for C=2 with shared transcendental:
//   d = x0 - x1;  L = log(1+exp(-|d|))          (target-independent!)
//   t==1: softplus(d)  = max(d,0)  + L
//   t==0: softplus(-d) = max(-d,0) + L = (|d|-max(d,0)) + L
__device__ __forceinline__ void acc2(float e0, float e1, int t,
                                     float& s0, float& s1, unsigned int& c1)
{
    float d  = e0 - e1;
    float ad = fabsf(d);
    float L  = __logf(1.f + __expf(-ad));
    float rp = fmaxf(d, 0.f);
    float rn = ad - rp;              // == max(-d, 0)
    s1 += t ? (rp + L) : 0.f;
    s0 += t ? 0.f : (rn + L);
    c1 += (t != 0);
}

__device__ __forceinline__ void acc_quad(v4f xa, v4f xb, v4i t,
                                         float& s0, float& s1, unsigned int& c1)
{
    acc2(xa[0], xa[1], t[0], s0, s1, c1);
    acc2(xa[2], xa[3], t[1], s0, s1, c1);
    acc2(xb[0], xb[1], t[2], s0, s1, c1);
    acc2(xb[2], xb[3], t[3], s0, s1, c1);
}

// Stage 1: grid-stride over quads of samples. All loads 16B lane-contiguous
// (measured-best layout: 2x float4 logits + 1x int4 targets per quad).
// For N=8.39M the x4 unroll covers each thread's ENTIRE assignment: all 12
// loads (192 B/thread) issue before any compute — maximal MLP. Nontemporal:
// read-once stream, avoid L2 allocation (defers fill-line writeback out of
// our window). Per-block partial sums to distinct slots, no atomics.
__global__ __launch_bounds__(BLOCK) void nll_partial(
    const v4f* __restrict__ x4,
    const v4i* __restrict__ t4,
    float* __restrict__ ps0,          // [NBLOCKS] sum(-logp | class0)
    float* __restrict__ ps1,          // [NBLOCKS] sum(-logp | class1)
    unsigned int* __restrict__ pc1,   // [NBLOCKS] count(class1)
    int nquads)
{
    int idx = blockIdx.x * BLOCK + threadIdx.x;
    int stride = gridDim.x * BLOCK;

    float s0 = 0.f, s1 = 0.f;
    unsigned int c1 = 0;

    int i = idx;
    for (; i + 3 * stride < nquads; i += 4 * stride) {
        int i1 = i + stride, i2 = i + 2 * stride, i3 = i + 3 * stride;
        v4f xa0 = __builtin_nontemporal_load(&x4[2 * i]);
        v4f xb0 = __builtin_nontemporal_load(&x4[2 * i + 1]);
        v4f xa1 = __builtin_nontemporal_load(&x4[2 * i1]);
        v4f xb1 = __builtin_nontemporal_load(&x4[2 * i1 + 1]);
        v4f xa2 = __builtin_nontemporal_load(&x4[2 * i2]);
        v4f xb2 = __builtin_nontemporal_load(&x4[2 * i2 + 1]);
        v4f xa3 = __builtin_nontemporal_load(&x4[2 * i3]);
        v4f xb3 = __builtin_nontemporal_load(&x4[2 * i3 + 1]);
        v4i t0  = __builtin_nontemporal_load(&t4[i]);
        v4i t1  = __builtin_nontemporal_load(&t4[i1]);
        v4i t2  = __builtin_nontemporal_load(&t4[i2]);
        v4i t3  = __builtin_nontemporal_load(&t4[i3]);
        acc_quad(xa0, xb0, t0, s0, s1, c1);
        acc_quad(xa1, xb1, t1, s0, s1, c1);
        acc_quad(xa2, xb2, t2, s0, s1, c1);
        acc_quad(xa3, xb3, t3, s0, s1, c1);
    }
    for (; i < nquads; i += stride) {
        v4f xa = __builtin_nontemporal_load(&x4[2 * i]);
        v4f xb = __builtin_nontemporal_load(&x4[2 * i + 1]);
        v4i t  = __builtin_nontemporal_load(&t4[i]);
        acc_quad(xa, xb, t, s0, s1, c1);
    }

    // wave64 reduce
    for (int off = 32; off > 0; off >>= 1) {
        s0 += __shfl_down(s0, off, 64);
        s1 += __shfl_down(s1, off, 64);
        c1 += __shfl_down(c1, off, 64);
    }

    __shared__ float sh0[BLOCK / 64];
    __shared__ float sh1[BLOCK / 64];
    __shared__ unsigned int shc[BLOCK / 64];

    int lane = threadIdx.x & 63;
    int wave = threadIdx.x >> 6;
    if (lane == 0) { sh0[wave] = s0; sh1[wave] = s1; shc[wave] = c1; }
    __syncthreads();

    if (threadIdx.x == 0) {
        float t0 = 0.f, t1 = 0.f;
        unsigned int tc = 0;
        for (int w = 0; w < BLOCK / 64; ++w) { t0 += sh0[w]; t1 += sh1[w]; tc += shc[w]; }
        ps0[blockIdx.x] = t0;   // plain store, unique address per block
        ps1[blockIdx.x] = t1;
        pc1[blockIdx.x] = tc;
    }
}

// Stage 2: one block reduces all partials, handles the (normally empty) tail,
// and writes the final scalar.
__global__ __launch_bounds__(BLOCK2) void nll_finalize(
    const float* __restrict__ ps0,
    const float* __restrict__ ps1,
    const unsigned int* __restrict__ pc1,
    const float* __restrict__ x,
    const int* __restrict__ tg,
    float* __restrict__ out,
    int P, int N, int tail_start)
{
    float s0 = 0.f, s1 = 0.f;
    unsigned int c1 = 0;
    for (int i = threadIdx.x; i < P; i += BLOCK2) {
        s0 += ps0[i];
        s1 += ps1[i];
        c1 += pc1[i];
    }

    for (int off = 32; off > 0; off >>= 1) {
        s0 += __shfl_down(s0, off, 64);
        s1 += __shfl_down(s1, off, 64);
        c1 += __shfl_down(c1, off, 64);
    }

    __shared__ float sh0[BLOCK2 / 64];
    __shared__ float sh1[BLOCK2 / 64];
    __shared__ unsigned int shc[BLOCK2 / 64];

    int lane = threadIdx.x & 63;
    int wave = threadIdx.x >> 6;
    if (lane == 0) { sh0[wave] = s0; sh1[wave] = s1; shc[wave] = c1; }
    __syncthreads();

    if (threadIdx.x == 0) {
        float t0 = 0.f, t1 = 0.f;
        unsigned int tc = 0;
        for (int w = 0; w < BLOCK2 / 64; ++w) { t0 += sh0[w]; t1 += sh1[w]; tc += shc[w]; }
        // tail samples (N % 4) — normally zero iterations
        for (int i = tail_start; i < N; ++i) {
            float a = x[2 * i], b = x[2 * i + 1];
            float d = a - b;
            float ad = fabsf(d);
            float L = __logf(1.f + __expf(-ad));
            float rp = fmaxf(d, 0.f);
            if (tg[i]) { t1 += rp + L; tc++; } else { t0 += (ad - rp) + L; }
        }
        unsigned int c0 = (unsigned int)N - tc;
        float r = (tc > 0) ? t1 / (float)tc : 0.f;
        float p = (c0 > 0) ? t0 / (float)c0 : 0.f;
        out[0] = p + r;
    }
}

// Fallback (tiny ws): atomic design, only used if ws_size < partial arrays.
__global__ void nll_atomic(const v4f* __restrict__ x4,
                           const v4i* __restrict__ t4,
                           float* __restrict__ wsf,
                           unsigned int* __restrict__ wsi,
                           int nquads)
{
    int idx = blockIdx.x * blockDim.x + threadIdx.x;
    int stride = gridDim.x * blockDim.x;
    float s0 = 0.f, s1 = 0.f;
    unsigned int c1 = 0;
    for (int i = idx; i < nquads; i += stride) {
        v4f xa = x4[2 * i];
        v4f xb = x4[2 * i + 1];
        v4i t  = t4[i];
        acc_quad(xa, xb, t, s0, s1, c1);
    }
    for (int off = 32; off > 0; off >>= 1) {
        s0 += __shfl_down(s0, off, 64);
        s1 += __shfl_down(s1, off, 64);
        c1 += __shfl_down(c1, off, 64);
    }
    __shared__ float sh0[4]; __shared__ float sh1[4]; __shared__ unsigned int shc[4];
    int lane = threadIdx.x & 63; int wave = threadIdx.x >> 6;
    if (lane == 0) { sh0[wave] = s0; sh1[wave] = s1; shc[wave] = c1; }
    __syncthreads();
    if (threadIdx.x == 0) {
        float t0 = 0.f, t1 = 0.f; unsigned int tc = 0;
        for (int w = 0; w < 4; ++w) { t0 += sh0[w]; t1 += sh1[w]; tc += shc[w]; }
        atomicAdd(&wsf[0], t0); atomicAdd(&wsf[1], t1); atomicAdd(&wsi[0], tc);
    }
}

__global__ void nll_atomic_fin(const float* __restrict__ x,
                               const int* __restrict__ tg,
                               const float* __restrict__ wsf,
                               const unsigned int* __restrict__ wsi,
                               float* __restrict__ out,
                               int N, int tail_start)
{
    float s0 = wsf[0], s1 = wsf[1];
    unsigned int c1 = wsi[0];
    for (int i = tail_start; i < N; ++i) {
        float a = x[2 * i], b = x[2 * i + 1];
        float d = a - b;
        float ad = fabsf(d);
        float L = __logf(1.f + __expf(-ad));
        float rp = fmaxf(d, 0.f);
        if (tg[i]) { s1 += rp + L; c1++; } else { s0 += (ad - rp) + L; }
    }
    unsigned int c0 = (unsigned int)N - c1;
    float r = (c1 > 0) ? s1 / (float)c1 : 0.f;
    float p = (c0 > 0) ? s0 / (float)c0 : 0.f;
    out[0] = p + r;
}

extern "C" void kernel_launch(void* const* d_in, const int* in_sizes, int n_in,
                              void* d_out, int out_size, void* d_ws, size_t ws_size,
                              hipStream_t stream) {
    const float* x = (const float*)d_in[0];
    const int* tg = (const int*)d_in[1];
    int N = in_sizes[1];
    float* out = (float*)d_out;

    int nquads = N / 4;
    int tail_start = nquads * 4;

    size_t need = (size_t)NBLOCKS * (4 + 4 + 4);  // ps0, ps1, pc1
    if (ws_size >= need) {
        float* ps0 = (float*)d_ws;
        float* ps1 = ps0 + NBLOCKS;
        unsigned int* pc1 = (unsigned int*)(ps1 + NBLOCKS);

        nll_partial<<<NBLOCKS, BLOCK, 0, stream>>>(
            (const v4f*)x, (const v4i*)tg, ps0, ps1, pc1, nquads);
        nll_finalize<<<1, BLOCK2, 0, stream>>>(
            ps0, ps1, pc1, x, tg, out, NBLOCKS, N, tail_start);
    } else {
        float* wsf = (float*)d_ws;
        unsigned int* wsi = (unsigned int*)((char*)d_ws + 8);
        hipMemsetAsync(d_ws, 0, 16, stream);
        nll_atomic<<<256, BLOCK, 0, stream>>>(
            (const v4f*)x, (const v4i*)tg, wsf, wsi, nquads);
        nll_atomic_fin<<<1, 1, 0, stream>>>(x, tg, wsf, wsi, out, N, tail_start);
    }
}

// Round 4
// 114.899 us; speedup vs baseline: 1.0527x; 1.0527x over previous
//
#include <hip/hip_runtime.h>

#define BLOCK 256
#define NBLOCKS 2048
#define BLOCK2 256

// -log softmax at target t for C=2 with shared transcendental:
//   d = x0 - x1;  L = log(1+exp(-|d|))          (target-independent!)
//   t==1: softplus(d)  = max(d,0)  + L
//   t==0: softplus(-d) = max(-d,0) + L = (|d|-max(d,0)) + L
__device__ __forceinline__ void acc2(float e0, float e1, int t,
                                     float& s0, float& s1, unsigned int& c1)
{
    float d  = e0 - e1;
    float ad = fabsf(d);
    float L  = __logf(1.f + __expf(-ad));
    float rp = fmaxf(d, 0.f);
    float rn = ad - rp;              // == max(-d, 0)
    s1 += t ? (rp + L) : 0.f;
    s0 += t ? 0.f : (rn + L);
    c1 += (t != 0);
}

// One float4 = logits of 2 samples (pair); one int2 = their targets.
__device__ __forceinline__ void acc_pair(float4 x, int2 t,
                                         float& s0, float& s1, unsigned int& c1)
{
    acc2(x.x, x.y, t.x, s0, s1, c1);
    acc2(x.z, x.w, t.y, s0, s1, c1);
}

// Stage 1: grid-stride over PAIRS. Consecutive lanes -> consecutive float4 /
// int2 addresses, so EVERY load instruction is fully lane-contiguous (16B and
// 8B per lane). Plain cached loads (NT measured -7us twice: it defeats the
// line reuse and re-fetches from HBM). Unroll x4, all 8 loads issued before
// any compute (96B in flight/thread, ~24 data VGPRs keeps kernel <=64 VGPR
// -> full 32 waves/CU). Per-block partial sums to distinct slots, no atomics;
// the kernel boundary provides cross-block ordering.
__global__ __launch_bounds__(BLOCK) void nll_partial(
    const float4* __restrict__ xp,
    const int2* __restrict__ tp,
    float* __restrict__ ps0,          // [NBLOCKS] sum(-logp | class0)
    float* __restrict__ ps1,          // [NBLOCKS] sum(-logp | class1)
    unsigned int* __restrict__ pc1,   // [NBLOCKS] count(class1)
    int npairs)
{
    int idx = blockIdx.x * BLOCK + threadIdx.x;
    int stride = gridDim.x * BLOCK;

    float s0 = 0.f, s1 = 0.f;
    unsigned int c1 = 0;

    int i = idx;
    for (; i + 3 * stride < npairs; i += 4 * stride) {
        int i1 = i + stride, i2 = i + 2 * stride, i3 = i + 3 * stride;
        float4 x0 = xp[i];
        float4 x1 = xp[i1];
        float4 x2 = xp[i2];
        float4 x3 = xp[i3];
        int2   t0 = tp[i];
        int2   t1 = tp[i1];
        int2   t2 = tp[i2];
        int2   t3 = tp[i3];
        acc_pair(x0, t0, s0, s1, c1);
        acc_pair(x1, t1, s0, s1, c1);
        acc_pair(x2, t2, s0, s1, c1);
        acc_pair(x3, t3, s0, s1, c1);
    }
    for (; i < npairs; i += stride) {
        float4 x = xp[i];
        int2   t = tp[i];
        acc_pair(x, t, s0, s1, c1);
    }

    // wave64 reduce
    for (int off = 32; off > 0; off >>= 1) {
        s0 += __shfl_down(s0, off, 64);
        s1 += __shfl_down(s1, off, 64);
        c1 += __shfl_down(c1, off, 64);
    }

    __shared__ float sh0[BLOCK / 64];
    __shared__ float sh1[BLOCK / 64];
    __shared__ unsigned int shc[BLOCK / 64];

    int lane = threadIdx.x & 63;
    int wave = threadIdx.x >> 6;
    if (lane == 0) { sh0[wave] = s0; sh1[wave] = s1; shc[wave] = c1; }
    __syncthreads();

    if (threadIdx.x == 0) {
        float t0 = 0.f, t1 = 0.f;
        unsigned int tc = 0;
        for (int w = 0; w < BLOCK / 64; ++w) { t0 += sh0[w]; t1 += sh1[w]; tc += shc[w]; }
        ps0[blockIdx.x] = t0;   // plain store, unique address per block
        ps1[blockIdx.x] = t1;
        pc1[blockIdx.x] = tc;
    }
}

// Stage 2: one block reduces all partials, handles the (normally empty) tail,
// and writes the final scalar.
__global__ __launch_bounds__(BLOCK2) void nll_finalize(
    const float* __restrict__ ps0,
    const float* __restrict__ ps1,
    const unsigned int* __restrict__ pc1,
    const float* __restrict__ x,
    const int* __restrict__ tg,
    float* __restrict__ out,
    int P, int N, int tail_start)
{
    float s0 = 0.f, s1 = 0.f;
    unsigned int c1 = 0;
    for (int i = threadIdx.x; i < P; i += BLOCK2) {
        s0 += ps0[i];
        s1 += ps1[i];
        c1 += pc1[i];
    }

    for (int off = 32; off > 0; off >>= 1) {
        s0 += __shfl_down(s0, off, 64);
        s1 += __shfl_down(s1, off, 64);
        c1 += __shfl_down(c1, off, 64);
    }

    __shared__ float sh0[BLOCK2 / 64];
    __shared__ float sh1[BLOCK2 / 64];
    __shared__ unsigned int shc[BLOCK2 / 64];

    int lane = threadIdx.x & 63;
    int wave = threadIdx.x >> 6;
    if (lane == 0) { sh0[wave] = s0; sh1[wave] = s1; shc[wave] = c1; }
    __syncthreads();

    if (threadIdx.x == 0) {
        float t0 = 0.f, t1 = 0.f;
        unsigned int tc = 0;
        for (int w = 0; w < BLOCK2 / 64; ++w) { t0 += sh0[w]; t1 += sh1[w]; tc += shc[w]; }
        // tail samples (N % 2) — normally zero iterations
        for (int i = tail_start; i < N; ++i) {
            float a = x[2 * i], b = x[2 * i + 1];
            float d = a - b;
            float ad = fabsf(d);
            float L = __logf(1.f + __expf(-ad));
            float rp = fmaxf(d, 0.f);
            if (tg[i]) { t1 += rp + L; tc++; } else { t0 += (ad - rp) + L; }
        }
        unsigned int c0 = (unsigned int)N - tc;
        float r = (tc > 0) ? t1 / (float)tc : 0.f;
        float p = (c0 > 0) ? t0 / (float)c0 : 0.f;
        out[0] = p + r;
    }
}

// Fallback (tiny ws): atomic design, only used if ws_size < partial arrays.
__global__ void nll_atomic(const float4* __restrict__ xp,
                           const int2* __restrict__ tp,
                           float* __restrict__ wsf,
                           unsigned int* __restrict__ wsi,
                           int npairs)
{
    int idx = blockIdx.x * blockDim.x + threadIdx.x;
    int stride = gridDim.x * blockDim.x;
    float s0 = 0.f, s1 = 0.f;
    unsigned int c1 = 0;
    for (int i = idx; i < npairs; i += stride) {
        float4 x = xp[i];
        int2   t = tp[i];
        acc_pair(x, t, s0, s1, c1);
    }
    for (int off = 32; off > 0; off >>= 1) {
        s0 += __shfl_down(s0, off, 64);
        s1 += __shfl_down(s1, off, 64);
        c1 += __shfl_down(c1, off, 64);
    }
    __shared__ float sh0[4]; __shared__ float sh1[4]; __shared__ unsigned int shc[4];
    int lane = threadIdx.x & 63; int wave = threadIdx.x >> 6;
    if (lane == 0) { sh0[wave] = s0; sh1[wave] = s1; shc[wave] = c1; }
    __syncthreads();
    if (threadIdx.x == 0) {
        float t0 = 0.f, t1 = 0.f; unsigned int tc = 0;
        for (int w = 0; w < 4; ++w) { t0 += sh0[w]; t1 += sh1[w]; tc += shc[w]; }
        atomicAdd(&wsf[0], t0); atomicAdd(&wsf[1], t1); atomicAdd(&wsi[0], tc);
    }
}

__global__ void nll_atomic_fin(const float* __restrict__ x,
                               const int* __restrict__ tg,
                               const float* __restrict__ wsf,
                               const unsigned int* __restrict__ wsi,
                               float* __restrict__ out,
                               int N, int tail_start)
{
    float s0 = wsf[0], s1 = wsf[1];
    unsigned int c1 = wsi[0];
    for (int i = tail_start; i < N; ++i) {
        float a = x[2 * i], b = x[2 * i + 1];
        float d = a - b;
        float ad = fabsf(d);
        float L = __logf(1.f + __expf(-ad));
        float rp = fmaxf(d, 0.f);
        if (tg[i]) { s1 += rp + L; c1++; } else { s0 += (ad - rp) + L; }
    }
    unsigned int c0 = (unsigned int)N - c1;
    float r = (c1 > 0) ? s1 / (float)c1 : 0.f;
    float p = (c0 > 0) ? s0 / (float)c0 : 0.f;
    out[0] = p + r;
}

extern "C" void kernel_launch(void* const* d_in, const int* in_sizes, int n_in,
                              void* d_out, int out_size, void* d_ws, size_t ws_size,
                              hipStream_t stream) {
    const float* x = (const float*)d_in[0];
    const int* tg = (const int*)d_in[1];
    int N = in_sizes[1];
    float* out = (float*)d_out;

    int npairs = N / 2;
    int tail_start = npairs * 2;

    size_t need = (size_t)NBLOCKS * (4 + 4 + 4);  // ps0, ps1, pc1
    if (ws_size >= need) {
        float* ps0 = (float*)d_ws;
        float* ps1 = ps0 + NBLOCKS;
        unsigned int* pc1 = (unsigned int*)(ps1 + NBLOCKS);

        nll_partial<<<NBLOCKS, BLOCK, 0, stream>>>(
            (const float4*)x, (const int2*)tg, ps0, ps1, pc1, npairs);
        nll_finalize<<<1, BLOCK2, 0, stream>>>(
            ps0, ps1, pc1, x, tg, out, NBLOCKS, N, tail_start);
    } else {
        float* wsf = (float*)d_ws;
        unsigned int* wsi = (unsigned int*)((char*)d_ws + 8);
        hipMemsetAsync(d_ws, 0, 16, stream);
        nll_atomic<<<256, BLOCK, 0, stream>>>(
            (const float4*)x, (const int2*)tg, wsf, wsi, npairs);
        nll_atomic_fin<<<1, 1, 0, stream>>>(x, tg, wsf, wsi, out, N, tail_start);
    }
}